// Round 2
// baseline (6997.829 us; speedup 1.0000x reference)
//
#include <hip/hip_runtime.h>
#include <math.h>

// ---------------- problem constants ----------------
#define S_LEN   2048
#define BATCH   2
#define HDIM    1024
#define NH      16
#define NKV     4
#define HD      64
#define NE      16
#define FFN_D   2048
#define TOKENS  4096        // S*B
#define QKV_OUT 1536        // (NH + 2*NKV)*HD
#define CAP     640         // ceil(TOKENS*2/16*1.25)
#define CAP1    641
#define NSLOT   8192        // TOKENS*2
#define CHUNK   64          // MoE capacity-row chunk (small-ws path)

// ---------------- workspace layout (float elements) ----------------
// small | A (ln1 out -> attn out -> ln2 out) | B (qkv -> expert buf -> h2) | C (h1)
#define OFF_SMALL 0UL                 // 24,576 floats: exp_idx, pos (int), gate
#define OFF_A     24576UL             // 4,194,304  (16 MB)
#define OFF_B     4218880UL           // 10,502,144 (40 MB); first 6,291,456 = qkv
#define OFF_C     14721024UL          // h1: full 21,004,288 (84 MB) or chunked 2,097,152 (8 MB)
#define FLOATS_BIG   35725312UL       // 142.9 MB needed for full-h1 path
#define FLOATS_SMALL 16818176UL       // 67.3 MB needed for chunked path

__device__ __forceinline__ float gelu_tanh(float x) {
    float x3 = x * x * x;
    return 0.5f * x * (1.0f + tanhf(0.7978845608028654f * (x + 0.044715f * x3)));
}

// ---------------- LayerNorm: one block per token row ----------------
__global__ __launch_bounds__(256) void ln_kernel(const float* __restrict__ x,
                                                 const float* __restrict__ w,
                                                 const float* __restrict__ b,
                                                 float* __restrict__ y) {
    int row = blockIdx.x;
    int tid = threadIdx.x;
    const float4* xr = (const float4*)(x + (size_t)row * HDIM);
    float4 v = xr[tid];
    float sum = v.x + v.y + v.z + v.w;
    float sq  = v.x*v.x + v.y*v.y + v.z*v.z + v.w*v.w;
    __shared__ float s1[256], s2[256];
    s1[tid] = sum; s2[tid] = sq;
    __syncthreads();
    for (int off = 128; off > 0; off >>= 1) {
        if (tid < off) { s1[tid] += s1[tid + off]; s2[tid] += s2[tid + off]; }
        __syncthreads();
    }
    float mu  = s1[0] * (1.0f / HDIM);
    float var = s2[0] * (1.0f / HDIM) - mu * mu;
    float rs  = rsqrtf(var + 1e-5f);
    float4 w4 = ((const float4*)w)[tid];
    float4 b4 = ((const float4*)b)[tid];
    float4 o;
    o.x = (v.x - mu) * rs * w4.x + b4.x;
    o.y = (v.y - mu) * rs * w4.y + b4.y;
    o.z = (v.z - mu) * rs * w4.z + b4.z;
    o.w = (v.w - mu) * rs * w4.w + b4.w;
    ((float4*)(y + (size_t)row * HDIM))[tid] = o;
}

// ---------------- generic batched GEMM: C[z] = A[z] @ B[z]^T ----------------
// A [M,K] row-major, B [N,K] row-major. 64x64 block tile, 4x4 per thread.
// act: 0 = none, 1 = gelu. resid: optional residual (stride sC per z).
__global__ __launch_bounds__(256) void gemm_bt(const float* __restrict__ A,
                                               const float* __restrict__ B,
                                               float* __restrict__ C,
                                               const float* __restrict__ resid,
                                               int M, int N, int K,
                                               long long sA, long long sB, long long sC,
                                               int act) {
    int z = blockIdx.z;
    const float* Ab = A + (long long)z * sA;
    const float* Bb = B + (long long)z * sB;
    float* Cb = C + (long long)z * sC;
    int bm = blockIdx.y << 6;
    int bn = blockIdx.x << 6;
    __shared__ __align__(16) float As[16][68];
    __shared__ __align__(16) float Bs[16][68];
    int tid = threadIdx.x;
    int tx = tid & 15, ty = tid >> 4;
    int rowL = tid >> 2;            // 0..63
    int kq = (tid & 3) << 2;        // 0,4,8,12
    float acc[4][4] = {};
    for (int kt = 0; kt < K; kt += 16) {
        float4 a4 = make_float4(0.f, 0.f, 0.f, 0.f);
        int ar = bm + rowL;
        if (ar < M) a4 = *(const float4*)(Ab + (long long)ar * K + kt + kq);
        float4 b4 = *(const float4*)(Bb + (long long)(bn + rowL) * K + kt + kq);
        __syncthreads();
        As[kq + 0][rowL] = a4.x; As[kq + 1][rowL] = a4.y;
        As[kq + 2][rowL] = a4.z; As[kq + 3][rowL] = a4.w;
        Bs[kq + 0][rowL] = b4.x; Bs[kq + 1][rowL] = b4.y;
        Bs[kq + 2][rowL] = b4.z; Bs[kq + 3][rowL] = b4.w;
        __syncthreads();
        #pragma unroll
        for (int kk = 0; kk < 16; ++kk) {
            float av[4], bv[4];
            #pragma unroll
            for (int i = 0; i < 4; ++i) { av[i] = As[kk][(ty << 2) + i]; bv[i] = Bs[kk][(tx << 2) + i]; }
            #pragma unroll
            for (int i = 0; i < 4; ++i)
                #pragma unroll
                for (int j = 0; j < 4; ++j)
                    acc[i][j] = fmaf(av[i], bv[j], acc[i][j]);
        }
    }
    #pragma unroll
    for (int i = 0; i < 4; ++i) {
        int row = bm + (ty << 2) + i;
        if (row >= M) continue;
        long long base = (long long)row * N + bn + (tx << 2);
        float4 v = make_float4(acc[i][0], acc[i][1], acc[i][2], acc[i][3]);
        if (act == 1) { v.x = gelu_tanh(v.x); v.y = gelu_tanh(v.y); v.z = gelu_tanh(v.z); v.w = gelu_tanh(v.w); }
        if (resid) {
            float4 r = *(const float4*)(resid + (long long)z * sC + base);
            v.x += r.x; v.y += r.y; v.z += r.z; v.w += r.w;
        }
        *(float4*)(Cb + base) = v;
    }
}

// ---------------- causal GQA attention: one wave per (q_pos, b, head) ----------------
// qkv row t = s*BATCH + b, layout [q(16*64) | k(4*64) | v(4*64)]
__global__ __launch_bounds__(64) void attn_kernel(const float* __restrict__ qkv,
                                                  float* __restrict__ attn_out) {
    int lane = threadIdx.x;
    int bid = blockIdx.x;
    int h  = bid & 15;
    int b  = (bid >> 4) & 1;
    int qs = bid >> 5;
    int kvh = h >> 2;
    __shared__ float qsm[64];
    __shared__ float Ks[64 * 65];
    int tq = qs * BATCH + b;
    qsm[lane] = qkv[(size_t)tq * QKV_OUT + h * HD + lane] * 0.125f;  // 1/sqrt(64)
    const float* kbase = qkv + 1024 + kvh * HD;
    const float* vbase = qkv + 1280 + kvh * HD;
    float m = -INFINITY, l = 0.f, o = 0.f;
    for (int c = 0; c <= qs; c += 64) {
        int nk = min(64, qs - c + 1);
        __syncthreads();   // previous chunk's LDS reads complete
        for (int r = 0; r < nk; ++r)
            Ks[r * 65 + lane] = kbase[(size_t)((c + r) * BATCH + b) * QKV_OUT + lane];
        __syncthreads();
        float s = -INFINITY;
        if (lane < nk) {
            float acc = 0.f;
            const float* kr = &Ks[lane * 65];
            #pragma unroll
            for (int d = 0; d < 64; ++d) acc = fmaf(qsm[d], kr[d], acc);
            s = acc;
        }
        float cm = s;
        #pragma unroll
        for (int off = 32; off; off >>= 1) cm = fmaxf(cm, __shfl_xor(cm, off));
        float mn = fmaxf(m, cm);
        float corr = expf(m - mn);           // 0 on first chunk (m=-inf)
        float p = (lane < nk) ? expf(s - mn) : 0.f;
        float ps = p;
        #pragma unroll
        for (int off = 32; off; off >>= 1) ps += __shfl_xor(ps, off);
        l = l * corr + ps;
        o *= corr;
        for (int r = 0; r < nk; ++r) {
            float pv = __shfl(p, r);
            o = fmaf(pv, vbase[(size_t)((c + r) * BATCH + b) * QKV_OUT + lane], o);
        }
        m = mn;
    }
    attn_out[(size_t)tq * HDIM + h * HD + lane] = o / l;
}

// ---------------- router: one wave per token, logits->softmax->top2 ----------------
__global__ __launch_bounds__(256) void router_kernel(const float* __restrict__ ln2,
                                                     const float* __restrict__ rw,
                                                     int* __restrict__ exp_idx,
                                                     float* __restrict__ gate) {
    int lane = threadIdx.x & 63;
    int w = threadIdx.x >> 6;
    int t = (blockIdx.x << 2) + w;
    float xr[16];
    #pragma unroll
    for (int i = 0; i < 16; ++i) xr[i] = ln2[(size_t)t * HDIM + i * 64 + lane];
    float lg[16];
    for (int e = 0; e < 16; ++e) {
        float a = 0.f;
        #pragma unroll
        for (int i = 0; i < 16; ++i) a = fmaf(xr[i], rw[e * HDIM + i * 64 + lane], a);
        #pragma unroll
        for (int off = 32; off; off >>= 1) a += __shfl_xor(a, off);
        lg[e] = a;
    }
    float mx = lg[0];
    #pragma unroll
    for (int e = 1; e < 16; ++e) mx = fmaxf(mx, lg[e]);
    float sum = 0.f;
    #pragma unroll
    for (int e = 0; e < 16; ++e) { lg[e] = expf(lg[e] - mx); sum += lg[e]; }
    float inv = 1.f / sum;
    int i1 = 0; float p1 = lg[0];
    #pragma unroll
    for (int e = 1; e < 16; ++e) if (lg[e] > p1) { p1 = lg[e]; i1 = e; }
    int i2 = -1; float p2 = -1.f;
    #pragma unroll
    for (int e = 0; e < 16; ++e) if (e != i1 && lg[e] > p2) { p2 = lg[e]; i2 = e; }
    if (lane == 0) {
        exp_idx[t * 2]     = i1;
        exp_idx[t * 2 + 1] = i2;
        gate[t * 2]        = p1 * inv;
        gate[t * 2 + 1]    = p2 * inv;
    }
}

// ---------------- slot-ordered capacity scan (single block) ----------------
__global__ __launch_bounds__(256) void scan_kernel(const int* __restrict__ exp_idx,
                                                   int* __restrict__ pos) {
    __shared__ int cnt[256][16];
    int tid = threadIdx.x;
    int c[16];
    #pragma unroll
    for (int e = 0; e < 16; ++e) c[e] = 0;
    int s0 = tid * 32;
    for (int i = 0; i < 32; ++i) {
        int ex = exp_idx[s0 + i];
        #pragma unroll
        for (int e = 0; e < 16; ++e) c[e] += (ex == e);
    }
    #pragma unroll
    for (int e = 0; e < 16; ++e) cnt[tid][e] = c[e];
    __syncthreads();
    if (tid < 16) {
        int run = 0;
        for (int i = 0; i < 256; ++i) { int t = cnt[i][tid]; cnt[i][tid] = run; run += t; }
    }
    __syncthreads();
    int off[16];
    #pragma unroll
    for (int e = 0; e < 16; ++e) off[e] = cnt[tid][e];
    for (int i = 0; i < 32; ++i) {
        int ex = exp_idx[s0 + i];
        #pragma unroll
        for (int e = 0; e < 16; ++e) if (ex == e) { pos[s0 + i] = off[e]; off[e]++; }
    }
}

// ---------------- scatter kept tokens into expert buffers ----------------
__global__ __launch_bounds__(256) void scatter_kernel(const float* __restrict__ ln2,
                                                      const int* __restrict__ exp_idx,
                                                      const int* __restrict__ pos,
                                                      float* __restrict__ buf) {
    int s = blockIdx.x;
    int p = pos[s];
    if (p >= CAP) return;
    int e = exp_idx[s];
    int tok = s >> 1;
    const float4* src = (const float4*)(ln2 + (size_t)tok * HDIM);
    float4* dst = (float4*)(buf + ((size_t)e * CAP1 + p) * HDIM);
    dst[threadIdx.x] = src[threadIdx.x];
}

// ---------------- combine: out = ha + sum_k gate*h2 (in-place on d_out) ----------------
__global__ __launch_bounds__(256) void combine_kernel(const float* __restrict__ h2,
                                                      const int* __restrict__ exp_idx,
                                                      const int* __restrict__ pos,
                                                      const float* __restrict__ gate,
                                                      float* __restrict__ out) {
    int t = blockIdx.x;
    int tid = threadIdx.x;
    float4 v = ((const float4*)(out + (size_t)t * HDIM))[tid];   // ha lives in d_out
    #pragma unroll
    for (int k = 0; k < 2; ++k) {
        int s = t * 2 + k;
        int p = pos[s];
        if (p < CAP) {
            float g = gate[s];
            float4 hv = ((const float4*)(h2 + ((size_t)exp_idx[s] * CAP1 + p) * HDIM))[tid];
            v.x = fmaf(g, hv.x, v.x); v.y = fmaf(g, hv.y, v.y);
            v.z = fmaf(g, hv.z, v.z); v.w = fmaf(g, hv.w, v.w);
        }
    }
    ((float4*)(out + (size_t)t * HDIM))[tid] = v;
}

extern "C" void kernel_launch(void* const* d_in, const int* in_sizes, int n_in,
                              void* d_out, int out_size, void* d_ws, size_t ws_size,
                              hipStream_t stream) {
    const float* hidden  = (const float*)d_in[0];
    const float* ln1w    = (const float*)d_in[1];
    const float* ln1b    = (const float*)d_in[2];
    const float* ln2w    = (const float*)d_in[3];
    const float* ln2b    = (const float*)d_in[4];
    const float* qkvw    = (const float*)d_in[5];
    const float* projw   = (const float*)d_in[6];
    const float* routerw = (const float*)d_in[7];
    const float* w1      = (const float*)d_in[8];
    const float* w2      = (const float*)d_in[9];

    float* ws      = (float*)d_ws;
    int*   exp_idx = (int*)(ws + OFF_SMALL);
    int*   pos     = exp_idx + NSLOT;
    float* gate    = (float*)(pos + NSLOT);
    float* bufA    = ws + OFF_A;     // ln1 out -> attn out -> ln2 out
    float* bufB    = ws + OFF_B;     // qkv (first 24MB) -> expert buf -> h2
    float* h1      = ws + OFF_C;     // full or chunked
    float* ha      = (float*)d_out;  // hidden_after_attn lives in d_out
    float* out     = (float*)d_out;

    // 1. LN1
    ln_kernel<<<TOKENS, 256, 0, stream>>>(hidden, ln1w, ln1b, bufA);
    // 2. QKV projection (into B region; dead before expert scatter reuses B)
    gemm_bt<<<dim3(QKV_OUT / 64, TOKENS / 64, 1), 256, 0, stream>>>(
        bufA, qkvw, bufB, nullptr, TOKENS, QKV_OUT, HDIM, 0, 0, 0, 0);
    // 3. causal GQA attention (overwrites A; ln1 dead)
    attn_kernel<<<S_LEN * BATCH * NH, 64, 0, stream>>>(bufB, bufA);
    // 4. output projection + residual -> hidden_after_attn (in d_out)
    gemm_bt<<<dim3(HDIM / 64, TOKENS / 64, 1), 256, 0, stream>>>(
        bufA, projw, ha, hidden, TOKENS, HDIM, HDIM, 0, 0, 0, 0);
    // 5. LN2 (overwrites A; attn dead)
    ln_kernel<<<TOKENS, 256, 0, stream>>>(ha, ln2w, ln2b, bufA);
    // 6. router: top-2 experts + gates
    router_kernel<<<TOKENS / 4, 256, 0, stream>>>(bufA, routerw, exp_idx, gate);
    // 7. capacity positions (slot order matters for drops)
    scan_kernel<<<1, 256, 0, stream>>>(exp_idx, pos);
    // 8. scatter into expert buffers (overwrites qkv in B; dead). Unwritten rows
    //    hold stale qkv/poison — finite, never read back by combine.
    scatter_kernel<<<NSLOT, 256, 0, stream>>>(bufA, exp_idx, pos, bufB);

    // 9/10. expert FC1 + gelu, FC2. Path depends only on ws_size (constant per
    // session — graph-capture safe). h2 aliases buf rows in place.
    if (ws_size >= FLOATS_BIG * sizeof(float)) {
        gemm_bt<<<dim3(FFN_D / 64, (CAP1 + 63) / 64, NE), 256, 0, stream>>>(
            bufB, w1, h1, nullptr, CAP1, FFN_D, HDIM,
            (long long)CAP1 * HDIM, (long long)FFN_D * HDIM, (long long)CAP1 * FFN_D, 1);
        gemm_bt<<<dim3(HDIM / 64, (CAP1 + 63) / 64, NE), 256, 0, stream>>>(
            h1, w2, bufB, nullptr, CAP1, HDIM, FFN_D,
            (long long)CAP1 * FFN_D, (long long)HDIM * FFN_D, (long long)CAP1 * HDIM, 0);
    } else {
        // chunked: h1 is [NE][CHUNK][FFN]; FC2 writes h2 back into the same buf
        // rows FC1 just consumed (exact-range in-place, stream-ordered).
        for (int c0 = 0; c0 < CAP1; c0 += CHUNK) {
            int rows = (CAP1 - c0 < CHUNK) ? (CAP1 - c0) : CHUNK;
            gemm_bt<<<dim3(FFN_D / 64, 1, NE), 256, 0, stream>>>(
                bufB + (size_t)c0 * HDIM, w1, h1, nullptr, rows, FFN_D, HDIM,
                (long long)CAP1 * HDIM, (long long)FFN_D * HDIM, (long long)CHUNK * FFN_D, 1);
            gemm_bt<<<dim3(HDIM / 64, 1, NE), 256, 0, stream>>>(
                h1, w2, bufB + (size_t)c0 * HDIM, nullptr, rows, HDIM, FFN_D,
                (long long)CHUNK * FFN_D, (long long)HDIM * FFN_D, (long long)CAP1 * HDIM, 0);
        }
    }
    // 11. gated combine + residual (ha already in d_out)
    combine_kernel<<<TOKENS, 256, 0, stream>>>(bufB, exp_idx, pos, gate, out);
}

// Round 3
// 2208.627 us; speedup vs baseline: 3.1684x; 3.1684x over previous
//
#include <hip/hip_runtime.h>
#include <math.h>

// ---------------- problem constants ----------------
#define S_LEN   2048
#define BATCH   2
#define HDIM    1024
#define NH      16
#define NKV     4
#define HD      64
#define NE      16
#define FFN_D   2048
#define TOKENS  4096        // S*B
#define QKV_OUT 1536        // (NH + 2*NKV)*HD
#define CAP     640         // ceil(TOKENS*2/16*1.25)
#define CAP1    641
#define NSLOT   8192        // TOKENS*2
#define CHUNK   64          // MoE capacity-row chunk (small-ws path)

// ---------------- workspace layout (float elements) ----------------
// small | A (ln1 out -> attn out -> ln2 out) | B (qkv -> expert buf -> h2) | C (h1)
#define OFF_SMALL 0UL                 // 24,576 floats: exp_idx, pos (int), gate
#define OFF_A     24576UL             // 4,194,304  (16 MB)
#define OFF_B     4218880UL           // 10,502,144 (40 MB); first 6,291,456 = qkv
#define OFF_C     14721024UL          // h1: full 21,004,288 (84 MB) or chunked 2,097,152 (8 MB)
#define FLOATS_BIG   35725312UL       // 142.9 MB needed for full-h1 path
#define FLOATS_SMALL 16818176UL       // 67.3 MB needed for chunked path

__device__ __forceinline__ float gelu_tanh(float x) {
    float x3 = x * x * x;
    return 0.5f * x * (1.0f + tanhf(0.7978845608028654f * (x + 0.044715f * x3)));
}

// ---------------- LayerNorm: one block per token row ----------------
__global__ __launch_bounds__(256) void ln_kernel(const float* __restrict__ x,
                                                 const float* __restrict__ w,
                                                 const float* __restrict__ b,
                                                 float* __restrict__ y) {
    int row = blockIdx.x;
    int tid = threadIdx.x;
    const float4* xr = (const float4*)(x + (size_t)row * HDIM);
    float4 v = xr[tid];
    float sum = v.x + v.y + v.z + v.w;
    float sq  = v.x*v.x + v.y*v.y + v.z*v.z + v.w*v.w;
    __shared__ float s1[256], s2[256];
    s1[tid] = sum; s2[tid] = sq;
    __syncthreads();
    for (int off = 128; off > 0; off >>= 1) {
        if (tid < off) { s1[tid] += s1[tid + off]; s2[tid] += s2[tid + off]; }
        __syncthreads();
    }
    float mu  = s1[0] * (1.0f / HDIM);
    float var = s2[0] * (1.0f / HDIM) - mu * mu;
    float rs  = rsqrtf(var + 1e-5f);
    float4 w4 = ((const float4*)w)[tid];
    float4 b4 = ((const float4*)b)[tid];
    float4 o;
    o.x = (v.x - mu) * rs * w4.x + b4.x;
    o.y = (v.y - mu) * rs * w4.y + b4.y;
    o.z = (v.z - mu) * rs * w4.z + b4.z;
    o.w = (v.w - mu) * rs * w4.w + b4.w;
    ((float4*)(y + (size_t)row * HDIM))[tid] = o;
}

// ---------------- generic batched GEMM: C[z] = A[z] @ B[z]^T ----------------
__global__ __launch_bounds__(256) void gemm_bt(const float* __restrict__ A,
                                               const float* __restrict__ B,
                                               float* __restrict__ C,
                                               const float* __restrict__ resid,
                                               int M, int N, int K,
                                               long long sA, long long sB, long long sC,
                                               int act) {
    int z = blockIdx.z;
    const float* Ab = A + (long long)z * sA;
    const float* Bb = B + (long long)z * sB;
    float* Cb = C + (long long)z * sC;
    int bm = blockIdx.y << 6;
    int bn = blockIdx.x << 6;
    __shared__ __align__(16) float As[16][68];
    __shared__ __align__(16) float Bs[16][68];
    int tid = threadIdx.x;
    int tx = tid & 15, ty = tid >> 4;
    int rowL = tid >> 2;            // 0..63
    int kq = (tid & 3) << 2;        // 0,4,8,12
    float acc[4][4] = {};
    for (int kt = 0; kt < K; kt += 16) {
        float4 a4 = make_float4(0.f, 0.f, 0.f, 0.f);
        int ar = bm + rowL;
        if (ar < M) a4 = *(const float4*)(Ab + (long long)ar * K + kt + kq);
        float4 b4 = *(const float4*)(Bb + (long long)(bn + rowL) * K + kt + kq);
        __syncthreads();
        As[kq + 0][rowL] = a4.x; As[kq + 1][rowL] = a4.y;
        As[kq + 2][rowL] = a4.z; As[kq + 3][rowL] = a4.w;
        Bs[kq + 0][rowL] = b4.x; Bs[kq + 1][rowL] = b4.y;
        Bs[kq + 2][rowL] = b4.z; Bs[kq + 3][rowL] = b4.w;
        __syncthreads();
        #pragma unroll
        for (int kk = 0; kk < 16; ++kk) {
            float av[4], bv[4];
            #pragma unroll
            for (int i = 0; i < 4; ++i) { av[i] = As[kk][(ty << 2) + i]; bv[i] = Bs[kk][(tx << 2) + i]; }
            #pragma unroll
            for (int i = 0; i < 4; ++i)
                #pragma unroll
                for (int j = 0; j < 4; ++j)
                    acc[i][j] = fmaf(av[i], bv[j], acc[i][j]);
        }
    }
    #pragma unroll
    for (int i = 0; i < 4; ++i) {
        int row = bm + (ty << 2) + i;
        if (row >= M) continue;
        long long base = (long long)row * N + bn + (tx << 2);
        float4 v = make_float4(acc[i][0], acc[i][1], acc[i][2], acc[i][3]);
        if (act == 1) { v.x = gelu_tanh(v.x); v.y = gelu_tanh(v.y); v.z = gelu_tanh(v.z); v.w = gelu_tanh(v.w); }
        if (resid) {
            float4 r = *(const float4*)(resid + (long long)z * sC + base);
            v.x += r.x; v.y += r.y; v.z += r.z; v.w += r.w;
        }
        *(float4*)(Cb + base) = v;
    }
}

// ---------------- tiled causal GQA flash attention ----------------
// One 256-thread block per (64-query tile, batch, head). Both S=Q*K^T and
// O+=P*V are 64x64x64 micro-GEMMs with 4x4 register tiles, float4 LDS reads.
// P reuses the K LDS buffer (dead after scores). Stride 68 floats: float4
// aligned; worst bank aliasing 2-way (free per m136).
__global__ __launch_bounds__(256) void attn_tile_kernel(const float* __restrict__ qkv,
                                                        float* __restrict__ attn_out) {
    int bid = blockIdx.x;
    int h   = bid & 15;
    int b   = (bid >> 4) & 1;
    int qt  = bid >> 5;             // 0..31
    int q0  = qt << 6;
    int kvh = h >> 2;
    int t   = threadIdx.x;
    int tx  = t & 15, ty = t >> 4;  // 4x4 micro-tile coords

    __shared__ __align__(16) float Qs[64 * 68];   // [d][q], pre-scaled
    __shared__ __align__(16) float KPs[64 * 68];  // K as [d][k]; then P as [k][q]
    __shared__ __align__(16) float Vs[64 * 68];   // [k][d]

    int r  = t >> 2;                // staging row 0..63
    int d0 = (t & 3) << 4;          // staging dim offset 0,16,32,48

    // stage Q once (transposed, scaled by 1/sqrt(64))
    {
        const float* qrow = qkv + ((size_t)(q0 + r) * BATCH + b) * QKV_OUT + h * HD + d0;
        #pragma unroll
        for (int u = 0; u < 16; u += 4) {
            float4 v = *(const float4*)(qrow + u);
            Qs[(d0 + u + 0) * 68 + r] = v.x * 0.125f;
            Qs[(d0 + u + 1) * 68 + r] = v.y * 0.125f;
            Qs[(d0 + u + 2) * 68 + r] = v.z * 0.125f;
            Qs[(d0 + u + 3) * 68 + r] = v.w * 0.125f;
        }
    }

    float m[4], l[4], o[4][4];
    #pragma unroll
    for (int i = 0; i < 4; ++i) {
        m[i] = -INFINITY; l[i] = 0.f;
        o[i][0] = o[i][1] = o[i][2] = o[i][3] = 0.f;
    }

    const float* kgbase = qkv + 1024 + kvh * HD;
    const float* vgbase = qkv + 1280 + kvh * HD;

    for (int c = 0; c <= q0; c += 64) {
        __syncthreads();   // prev chunk's P/V reads complete before restage
        {   // stage K (transposed [d][k]) and V (natural [k][d])
            const float* krow = kgbase + ((size_t)(c + r) * BATCH + b) * QKV_OUT + d0;
            #pragma unroll
            for (int u = 0; u < 16; u += 4) {
                float4 v = *(const float4*)(krow + u);
                KPs[(d0 + u + 0) * 68 + r] = v.x;
                KPs[(d0 + u + 1) * 68 + r] = v.y;
                KPs[(d0 + u + 2) * 68 + r] = v.z;
                KPs[(d0 + u + 3) * 68 + r] = v.w;
            }
            const float* vrow = vgbase + ((size_t)(c + r) * BATCH + b) * QKV_OUT + d0;
            #pragma unroll
            for (int u = 0; u < 16; u += 4)
                *(float4*)&Vs[r * 68 + d0 + u] = *(const float4*)(vrow + u);
        }
        __syncthreads();

        // scores: S[4q][4k] = Q.K^T micro-GEMM
        float acc[4][4] = {};
        #pragma unroll 8
        for (int d = 0; d < 64; ++d) {
            float4 av = *(const float4*)&Qs[d * 68 + (ty << 2)];
            float4 bv = *(const float4*)&KPs[d * 68 + (tx << 2)];
            float a4[4] = {av.x, av.y, av.z, av.w};
            float b4[4] = {bv.x, bv.y, bv.z, bv.w};
            #pragma unroll
            for (int i = 0; i < 4; ++i)
                #pragma unroll
                for (int j = 0; j < 4; ++j)
                    acc[i][j] = fmaf(a4[i], b4[j], acc[i][j]);
        }
        if (c == q0) {  // diagonal chunk: mask k > q
            #pragma unroll
            for (int i = 0; i < 4; ++i) {
                int q = q0 + (ty << 2) + i;
                #pragma unroll
                for (int j = 0; j < 4; ++j)
                    if (c + (tx << 2) + j > q) acc[i][j] = -INFINITY;
            }
        }
        __syncthreads();   // K reads done before P overwrites KPs

        // online softmax per q-row; row group = 16 lanes sharing (lane>>4)
        #pragma unroll
        for (int i = 0; i < 4; ++i) {
            float rm = fmaxf(fmaxf(acc[i][0], acc[i][1]), fmaxf(acc[i][2], acc[i][3]));
            #pragma unroll
            for (int off = 8; off; off >>= 1) rm = fmaxf(rm, __shfl_xor(rm, off));
            float mn = fmaxf(m[i], rm);
            float corr = __expf(m[i] - mn);
            float ps = 0.f;
            #pragma unroll
            for (int j = 0; j < 4; ++j) { float p = __expf(acc[i][j] - mn); acc[i][j] = p; ps += p; }
            #pragma unroll
            for (int off = 8; off; off >>= 1) ps += __shfl_xor(ps, off);
            l[i] = l[i] * corr + ps;
            m[i] = mn;
            #pragma unroll
            for (int j = 0; j < 4; ++j) o[i][j] *= corr;
            // write P transposed: Ps[k][q]
            #pragma unroll
            for (int j = 0; j < 4; ++j)
                KPs[((tx << 2) + j) * 68 + (ty << 2) + i] = acc[i][j];
        }
        __syncthreads();

        // O += P.V micro-GEMM (contraction over k)
        #pragma unroll 8
        for (int k = 0; k < 64; ++k) {
            float4 av = *(const float4*)&KPs[k * 68 + (ty << 2)];
            float4 bv = *(const float4*)&Vs[k * 68 + (tx << 2)];
            float a4[4] = {av.x, av.y, av.z, av.w};
            float b4[4] = {bv.x, bv.y, bv.z, bv.w};
            #pragma unroll
            for (int i = 0; i < 4; ++i)
                #pragma unroll
                for (int j = 0; j < 4; ++j)
                    o[i][j] = fmaf(a4[i], b4[j], o[i][j]);
        }
    }

    #pragma unroll
    for (int i = 0; i < 4; ++i) {
        int q = q0 + (ty << 2) + i;
        float inv = 1.f / l[i];
        float4 v = make_float4(o[i][0] * inv, o[i][1] * inv, o[i][2] * inv, o[i][3] * inv);
        *(float4*)(attn_out + ((size_t)q * BATCH + b) * HDIM + h * HD + (tx << 2)) = v;
    }
}

// ---------------- router: one wave per token, logits->softmax->top2 ----------------
__global__ __launch_bounds__(256) void router_kernel(const float* __restrict__ ln2,
                                                     const float* __restrict__ rw,
                                                     int* __restrict__ exp_idx,
                                                     float* __restrict__ gate) {
    int lane = threadIdx.x & 63;
    int w = threadIdx.x >> 6;
    int t = (blockIdx.x << 2) + w;
    float xr[16];
    #pragma unroll
    for (int i = 0; i < 16; ++i) xr[i] = ln2[(size_t)t * HDIM + i * 64 + lane];
    float lg[16];
    for (int e = 0; e < 16; ++e) {
        float a = 0.f;
        #pragma unroll
        for (int i = 0; i < 16; ++i) a = fmaf(xr[i], rw[e * HDIM + i * 64 + lane], a);
        #pragma unroll
        for (int off = 32; off; off >>= 1) a += __shfl_xor(a, off);
        lg[e] = a;
    }
    float mx = lg[0];
    #pragma unroll
    for (int e = 1; e < 16; ++e) mx = fmaxf(mx, lg[e]);
    float sum = 0.f;
    #pragma unroll
    for (int e = 0; e < 16; ++e) { lg[e] = expf(lg[e] - mx); sum += lg[e]; }
    float inv = 1.f / sum;
    int i1 = 0; float p1 = lg[0];
    #pragma unroll
    for (int e = 1; e < 16; ++e) if (lg[e] > p1) { p1 = lg[e]; i1 = e; }
    int i2 = -1; float p2 = -1.f;
    #pragma unroll
    for (int e = 0; e < 16; ++e) if (e != i1 && lg[e] > p2) { p2 = lg[e]; i2 = e; }
    if (lane == 0) {
        exp_idx[t * 2]     = i1;
        exp_idx[t * 2 + 1] = i2;
        gate[t * 2]        = p1 * inv;
        gate[t * 2 + 1]    = p2 * inv;
    }
}

// ---------------- slot-ordered capacity scan (single block) ----------------
__global__ __launch_bounds__(256) void scan_kernel(const int* __restrict__ exp_idx,
                                                   int* __restrict__ pos) {
    __shared__ int cnt[256][16];
    int tid = threadIdx.x;
    int c[16];
    #pragma unroll
    for (int e = 0; e < 16; ++e) c[e] = 0;
    int s0 = tid * 32;
    for (int i = 0; i < 32; ++i) {
        int ex = exp_idx[s0 + i];
        #pragma unroll
        for (int e = 0; e < 16; ++e) c[e] += (ex == e);
    }
    #pragma unroll
    for (int e = 0; e < 16; ++e) cnt[tid][e] = c[e];
    __syncthreads();
    if (tid < 16) {
        int run = 0;
        for (int i = 0; i < 256; ++i) { int t = cnt[i][tid]; cnt[i][tid] = run; run += t; }
    }
    __syncthreads();
    int off[16];
    #pragma unroll
    for (int e = 0; e < 16; ++e) off[e] = cnt[tid][e];
    for (int i = 0; i < 32; ++i) {
        int ex = exp_idx[s0 + i];
        #pragma unroll
        for (int e = 0; e < 16; ++e) if (ex == e) { pos[s0 + i] = off[e]; off[e]++; }
    }
}

// ---------------- scatter kept tokens into expert buffers ----------------
__global__ __launch_bounds__(256) void scatter_kernel(const float* __restrict__ ln2,
                                                      const int* __restrict__ exp_idx,
                                                      const int* __restrict__ pos,
                                                      float* __restrict__ buf) {
    int s = blockIdx.x;
    int p = pos[s];
    if (p >= CAP) return;
    int e = exp_idx[s];
    int tok = s >> 1;
    const float4* src = (const float4*)(ln2 + (size_t)tok * HDIM);
    float4* dst = (float4*)(buf + ((size_t)e * CAP1 + p) * HDIM);
    dst[threadIdx.x] = src[threadIdx.x];
}

// ---------------- combine: out = ha + sum_k gate*h2 (in-place on d_out) ----------------
__global__ __launch_bounds__(256) void combine_kernel(const float* __restrict__ h2,
                                                      const int* __restrict__ exp_idx,
                                                      const int* __restrict__ pos,
                                                      const float* __restrict__ gate,
                                                      float* __restrict__ out) {
    int t = blockIdx.x;
    int tid = threadIdx.x;
    float4 v = ((const float4*)(out + (size_t)t * HDIM))[tid];   // ha lives in d_out
    #pragma unroll
    for (int k = 0; k < 2; ++k) {
        int s = t * 2 + k;
        int p = pos[s];
        if (p < CAP) {
            float g = gate[s];
            float4 hv = ((const float4*)(h2 + ((size_t)exp_idx[s] * CAP1 + p) * HDIM))[tid];
            v.x = fmaf(g, hv.x, v.x); v.y = fmaf(g, hv.y, v.y);
            v.z = fmaf(g, hv.z, v.z); v.w = fmaf(g, hv.w, v.w);
        }
    }
    ((float4*)(out + (size_t)t * HDIM))[tid] = v;
}

extern "C" void kernel_launch(void* const* d_in, const int* in_sizes, int n_in,
                              void* d_out, int out_size, void* d_ws, size_t ws_size,
                              hipStream_t stream) {
    const float* hidden  = (const float*)d_in[0];
    const float* ln1w    = (const float*)d_in[1];
    const float* ln1b    = (const float*)d_in[2];
    const float* ln2w    = (const float*)d_in[3];
    const float* ln2b    = (const float*)d_in[4];
    const float* qkvw    = (const float*)d_in[5];
    const float* projw   = (const float*)d_in[6];
    const float* routerw = (const float*)d_in[7];
    const float* w1      = (const float*)d_in[8];
    const float* w2      = (const float*)d_in[9];

    float* ws      = (float*)d_ws;
    int*   exp_idx = (int*)(ws + OFF_SMALL);
    int*   pos     = exp_idx + NSLOT;
    float* gate    = (float*)(pos + NSLOT);
    float* bufA    = ws + OFF_A;     // ln1 out -> attn out -> ln2 out
    float* bufB    = ws + OFF_B;     // qkv (first 24MB) -> expert buf -> h2
    float* h1      = ws + OFF_C;     // full or chunked
    float* ha      = (float*)d_out;  // hidden_after_attn lives in d_out
    float* out     = (float*)d_out;

    // 1. LN1
    ln_kernel<<<TOKENS, 256, 0, stream>>>(hidden, ln1w, ln1b, bufA);
    // 2. QKV projection
    gemm_bt<<<dim3(QKV_OUT / 64, TOKENS / 64, 1), 256, 0, stream>>>(
        bufA, qkvw, bufB, nullptr, TOKENS, QKV_OUT, HDIM, 0, 0, 0, 0);
    // 3. tiled causal GQA attention (overwrites A; ln1 dead)
    attn_tile_kernel<<<(S_LEN / 64) * BATCH * NH, 256, 0, stream>>>(bufB, bufA);
    // 4. output projection + residual -> hidden_after_attn (in d_out)
    gemm_bt<<<dim3(HDIM / 64, TOKENS / 64, 1), 256, 0, stream>>>(
        bufA, projw, ha, hidden, TOKENS, HDIM, HDIM, 0, 0, 0, 0);
    // 5. LN2 (overwrites A; attn dead)
    ln_kernel<<<TOKENS, 256, 0, stream>>>(ha, ln2w, ln2b, bufA);
    // 6. router
    router_kernel<<<TOKENS / 4, 256, 0, stream>>>(bufA, routerw, exp_idx, gate);
    // 7. capacity positions
    scan_kernel<<<1, 256, 0, stream>>>(exp_idx, pos);
    // 8. scatter into expert buffers (overwrites qkv in B; dead)
    scatter_kernel<<<NSLOT, 256, 0, stream>>>(bufA, exp_idx, pos, bufB);

    // 9/10. expert FC1+gelu, FC2 (path fixed by ws_size — graph-capture safe)
    if (ws_size >= FLOATS_BIG * sizeof(float)) {
        gemm_bt<<<dim3(FFN_D / 64, (CAP1 + 63) / 64, NE), 256, 0, stream>>>(
            bufB, w1, h1, nullptr, CAP1, FFN_D, HDIM,
            (long long)CAP1 * HDIM, (long long)FFN_D * HDIM, (long long)CAP1 * FFN_D, 1);
        gemm_bt<<<dim3(HDIM / 64, (CAP1 + 63) / 64, NE), 256, 0, stream>>>(
            h1, w2, bufB, nullptr, CAP1, HDIM, FFN_D,
            (long long)CAP1 * FFN_D, (long long)HDIM * FFN_D, (long long)CAP1 * HDIM, 0);
    } else {
        for (int c0 = 0; c0 < CAP1; c0 += CHUNK) {
            int rows = (CAP1 - c0 < CHUNK) ? (CAP1 - c0) : CHUNK;
            gemm_bt<<<dim3(FFN_D / 64, 1, NE), 256, 0, stream>>>(
                bufB + (size_t)c0 * HDIM, w1, h1, nullptr, rows, FFN_D, HDIM,
                (long long)CAP1 * HDIM, (long long)FFN_D * HDIM, (long long)CHUNK * FFN_D, 1);
            gemm_bt<<<dim3(HDIM / 64, 1, NE), 256, 0, stream>>>(
                h1, w2, bufB + (size_t)c0 * HDIM, nullptr, rows, HDIM, FFN_D,
                (long long)CHUNK * FFN_D, (long long)HDIM * FFN_D, (long long)CAP1 * HDIM, 0);
        }
    }
    // 11. gated combine + residual
    combine_kernel<<<TOKENS, 256, 0, stream>>>(bufB, exp_idx, pos, gate, out);
}